// Round 16
// baseline (218.614 us; speedup 1.0000x reference)
//
#include <hip/hip_runtime.h>
#include <hip/hip_fp16.h>
#include <math.h>

#define B_ 32
#define P_ 2048
#define N_ 65536
#define K_ 16
#define L_ 8
#define F_ 64
#define KS_ 5
#define KS3_ 125
#define NC_ 40
#define H_ 256
#define EPS_ 1e-5f
#define QPB_ 64      // queries per block
#define SEG_ 4       // segment lanes per query

// exact same fp expression everywhere (pinned fmaf order)
__device__ __forceinline__ float distf(float4 C, float nx, float ny, float nz, float qs) {
    return fmaf(C.x, nx, fmaf(C.y, ny, fmaf(C.z, nz, C.w))) + qs;
}

// compare-exchange (ascending): 2 inst
#define CES(a, b) { unsigned _mn = min(a, b); b = max(a, b); a = _mn; }

// Batcher odd-even mergesort of 8 (19 CE)
__device__ __forceinline__ void sort8(unsigned& e0, unsigned& e1, unsigned& e2, unsigned& e3,
                                      unsigned& e4, unsigned& e5, unsigned& e6, unsigned& e7) {
    CES(e0, e1) CES(e2, e3) CES(e4, e5) CES(e6, e7)
    CES(e0, e2) CES(e1, e3) CES(e4, e6) CES(e5, e7)
    CES(e1, e2) CES(e5, e6)
    CES(e0, e4) CES(e1, e5) CES(e2, e6) CES(e3, e7)
    CES(e2, e4) CES(e3, e5)
    CES(e1, e2) CES(e3, e4) CES(e5, e6)
}

// ascending bitonic merge of a bitonic 16-sequence (32 CE, fully static)
__device__ __forceinline__ void bitmerge16(unsigned (&a)[16]) {
#pragma unroll
    for (int dd = 8; dd >= 1; dd >>= 1)
#pragma unroll
        for (int k2 = 0; k2 < 16; k2 += 2 * dd)
#pragma unroll
            for (int i2 = k2; i2 < k2 + dd; i2++)
                CES(a[i2], a[i2 + dd])
}

// full sort of 16 keys
__device__ __forceinline__ void sort16(unsigned (&a)[16]) {
    sort8(a[0], a[1], a[2], a[3], a[4], a[5], a[6], a[7]);
    sort8(a[8], a[9], a[10], a[11], a[12], a[13], a[14], a[15]);
    unsigned t;
    t = a[8];  a[8]  = a[15]; a[15] = t;
    t = a[9];  a[9]  = a[14]; a[14] = t;
    t = a[10]; a[10] = a[13]; a[13] = t;
    t = a[11]; a[11] = a[12]; a[12] = t;
    bitmerge16(a);
}

// Flush 8 buffered keys into sorted-ascending bu[16] (== 8 sorted-inserts)
__device__ __forceinline__ void flush8(unsigned (&bu)[16],
                                       unsigned& e0, unsigned& e1, unsigned& e2, unsigned& e3,
                                       unsigned& e4, unsigned& e5, unsigned& e6, unsigned& e7,
                                       unsigned& thr) {
    sort8(e0, e1, e2, e3, e4, e5, e6, e7);
    CES(bu[8],  e7) CES(bu[9],  e6) CES(bu[10], e5) CES(bu[11], e4)
    CES(bu[12], e3) CES(bu[13], e2) CES(bu[14], e1) CES(bu[15], e0)
    bitmerge16(bu);
    e0 = e1 = e2 = e3 = e4 = e5 = e6 = e7 = 0xFFFFFFFFu;
    unsigned t16 = bu[15];          // share threshold across the 4 seg-lanes
    t16 = min(t16, (unsigned)__shfl_xor((int)t16, 1, 64));
    t16 = min(t16, (unsigned)__shfl_xor((int)t16, 2, 64));
    thr = min(thr, t16);
}

// ---- Kernel 1: KNN + geometry (unchanged from round 15) ----
__global__ __launch_bounds__(256, 2) void knn_geom_kernel(const float* __restrict__ pos,
                                                          float* __restrict__ dcn) {
    __shared__ float4 cloud[P_ + 8];             // 32 KB + pad
    int b = blockIdx.x >> 5, tile = blockIdx.x & 31;
    int base = b * P_;
    int t = threadIdx.x;
    for (int j = t; j < P_; j += 256) {
        float x = pos[(base + j) * 3 + 0];
        float y = pos[(base + j) * 3 + 1];
        float z = pos[(base + j) * 3 + 2];
        cloud[j] = make_float4(x, y, z, x * x + y * y + z * z);
    }
    if (t < 8) cloud[P_ + t] = make_float4(0.f, 0.f, 0.f, 1e30f);  // pad: huge d
    __syncthreads();

    int s = t & 3;                                // segment lane
    int il = tile * QPB_ + (t >> 2);              // this lane's query
    float4 Q = cloud[il];
    float nx = -2.f * Q.x, ny = -2.f * Q.y, nz = -2.f * Q.z, qs = Q.w;

    int j0 = s << 9, off = s << 1;

    // ---- warm-start: candidates [off, off+15] -> sorted bu, fresh thr ----
    unsigned bu[16];
#pragma unroll
    for (int m = 0; m < 16; m++) {
        int j_ = j0 + off + m;
        float4 Cv = cloud[j_];
        float d_ = distf(Cv, nx, ny, nz, qs);
        bu[m] = (__float_as_uint(fmaxf(d_, 0.f)) & 0xFFFFF800u) | (unsigned)j_;
    }
    sort16(bu);
    unsigned thr;
    {
        unsigned t16 = bu[15];
        t16 = min(t16, (unsigned)__shfl_xor((int)t16, 1, 64));
        t16 = min(t16, (unsigned)__shfl_xor((int)t16, 2, 64));
        thr = t16;
    }

    unsigned e0 = ~0u, e1 = ~0u, e2 = ~0u, e3 = ~0u,
             e4 = ~0u, e5 = ~0u, e6 = ~0u, e7 = ~0u;

#define VISITL(Cv, Jv) {                                                         \
        float d_ = distf(Cv, nx, ny, nz, qs);                                    \
        unsigned key_ = (__float_as_uint(fmaxf(d_, 0.f)) & 0xFFFFF800u)          \
                        | (unsigned)(Jv);                                        \
        bool a_ = (key_ < thr);                                                  \
        e7 = a_ ? e6 : e7;  e6 = a_ ? e5 : e6;  e5 = a_ ? e4 : e5;               \
        e4 = a_ ? e3 : e4;  e3 = a_ ? e2 : e3;  e2 = a_ ? e1 : e2;               \
        e1 = a_ ? e0 : e1;  e0 = a_ ? key_ : e0;                                 \
    }
#define VISITP(Cv, Jv, P) {                                                      \
        float d_ = distf(Cv, nx, ny, nz, qs);                                    \
        unsigned key_ = (__float_as_uint(fmaxf(d_, 0.f)) & 0xFFFFF800u)          \
                        | (unsigned)(Jv);                                        \
        bool a_ = (key_ < thr) && (P);                                           \
        e7 = a_ ? e6 : e7;  e6 = a_ ? e5 : e6;  e5 = a_ ? e4 : e5;               \
        e4 = a_ ? e3 : e4;  e3 = a_ ? e2 : e3;  e2 = a_ ? e1 : e2;               \
        e1 = a_ ? e0 : e1;  e0 = a_ ? key_ : e0;                                 \
    }

    // ---- main: 488 linear visits, jj in [off+16, off+503] ----
    const float4* cp = &cloud[j0 + off + 16];
    int jc = j0 + off + 16;
    for (int v = 0; v < 488; v += 4) {
        float4 a0 = cp[v + 0], a1 = cp[v + 1], a2 = cp[v + 2], a3 = cp[v + 3];
        VISITL(a0, jc + 0)
        VISITL(a1, jc + 1)
        VISITL(a2, jc + 2)
        VISITL(a3, jc + 3)
        jc += 4;
        if (__any(e4 != 0xFFFFFFFFu))
            flush8(bu, e0, e1, e2, e3, e4, e5, e6, e7, thr);
    }
    // ---- epilogue: v = 488..495, accept iff v < 496-off (pad reads masked) --
    {
        int vlim = 496 - off;
#pragma unroll
        for (int v = 488; v < 492; v++) {
            float4 a0 = cp[v];
            VISITP(a0, jc, v < vlim) jc++;
        }
        if (__any(e4 != 0xFFFFFFFFu))
            flush8(bu, e0, e1, e2, e3, e4, e5, e6, e7, thr);
#pragma unroll
        for (int v = 492; v < 496; v++) {
            float4 a0 = cp[v];
            VISITP(a0, jc, v < vlim) jc++;
        }
        if (__any(e4 != 0xFFFFFFFFu))
            flush8(bu, e0, e1, e2, e3, e4, e5, e6, e7, thr);
    }
    // ---- head tail: [0, off) ----
    {
#pragma unroll
        for (int u = 0; u < 4; u++) {
            float4 a0 = cloud[j0 + u];
            VISITP(a0, j0 + u, u < off)
        }
        if (__any(e4 != 0xFFFFFFFFu))
            flush8(bu, e0, e1, e2, e3, e4, e5, e6, e7, thr);
#pragma unroll
        for (int u = 4; u < 6; u++) {
            float4 a0 = cloud[j0 + u];
            VISITP(a0, j0 + u, u < off)
        }
    }
    flush8(bu, e0, e1, e2, e3, e4, e5, e6, e7, thr);   // drain
#undef VISITL
#undef VISITP

    // ---- self-removal: owner lane's bu[0] is self (global min key) ----
    {
        bool own = (s == (il >> 9));
#pragma unroll
        for (int m = 0; m < 15; m++) bu[m] = own ? bu[m + 1] : bu[m];
        bu[15] = own ? 0xFFFFFFFFu : bu[15];
    }

    // ---- 2 bitonic rounds: all 4 seg-lanes -> sorted union-top-16 ----
#pragma unroll
    for (int mask = 1; mask <= 2; mask <<= 1) {
        unsigned o[16];
#pragma unroll
        for (int i = 0; i < 16; i++)
            o[i] = (unsigned)__shfl_xor((int)bu[15 - i], mask, 64);  // partner reversed
#pragma unroll
        for (int i = 0; i < 16; i++) bu[i] = min(bu[i], o[i]);       // half-cleaner
        bitmerge16(bu);
    }

    // ---- geometry: cov over L=8, 5x QR (LAPACK Householder), dc ----
    float px = Q.x, py = Q.y, pz = Q.z;
    float A[3][3];
    {
        float a00 = 0, a01 = 0, a02 = 0, a11 = 0, a12 = 0, a22 = 0;
#pragma unroll
        for (int l = 0; l < L_; l++) {
            float4 Cv = cloud[bu[l] & 0x7FF];
            float ccx = Cv.x - px, ccy = Cv.y - py, ccz = Cv.z - pz;
            a00 += ccx * ccx; a01 += ccx * ccy; a02 += ccx * ccz;
            a11 += ccy * ccy; a12 += ccy * ccz; a22 += ccz * ccz;
        }
        A[0][0] = a00; A[0][1] = a01; A[0][2] = a02;
        A[1][0] = a01; A[1][1] = a11; A[1][2] = a12;
        A[2][0] = a02; A[2][1] = a12; A[2][2] = a22;
    }
    float Vt[3][3] = {{1.f, 0.f, 0.f}, {0.f, 1.f, 0.f}, {0.f, 0.f, 1.f}};

    for (int it = 0; it < 5; it++) {
        float M00 = A[0][0], M01 = A[0][1], M02 = A[0][2];
        float M10 = A[1][0], M11 = A[1][1], M12 = A[1][2];
        float M20 = A[2][0], M21 = A[2][1], M22 = A[2][2];
        float tau0 = 0.f, v1 = 0.f, v2 = 0.f;
        float xn2 = M10 * M10 + M20 * M20;
        if (xn2 != 0.f) {
            float beta = -copysignf(sqrtf(M00 * M00 + xn2), M00);
            tau0 = (beta - M00) / beta;
            float inv = 1.f / (M00 - beta);
            v1 = M10 * inv; v2 = M20 * inv;
            float sc;
            sc = tau0 * (M01 + v1 * M11 + v2 * M21); M01 -= sc; M11 -= v1 * sc; M21 -= v2 * sc;
            sc = tau0 * (M02 + v1 * M12 + v2 * M22); M02 -= sc; M12 -= v1 * sc; M22 -= v2 * sc;
            M00 = beta;
        }
        float tau1 = 0.f, u2 = 0.f;
        if (M21 != 0.f) {
            float beta1 = -copysignf(sqrtf(M11 * M11 + M21 * M21), M11);
            tau1 = (beta1 - M11) / beta1;
            u2 = M21 / (M11 - beta1);
            float sc = tau1 * (M12 + u2 * M22); M12 -= sc; M22 -= u2 * sc;
            M11 = beta1;
        }
        float h11 = 1.f - tau1, h12 = -tau1 * u2, h22 = 1.f - tau1 * u2 * u2;
        float Qm[3][3];
        Qm[0][0] = 1.f - tau0;
        Qm[1][0] = -v1 * tau0;
        Qm[2][0] = -v2 * tau0;
        float t1 = tau0 * (v1 * h11 + v2 * h12);
        Qm[0][1] = -t1;
        Qm[1][1] = h11 - v1 * t1;
        Qm[2][1] = h12 - v2 * t1;
        float t2 = tau0 * (v1 * h12 + v2 * h22);
        Qm[0][2] = -t2;
        Qm[1][2] = h12 - v1 * t2;
        Qm[2][2] = h22 - v2 * t2;
        A[0][0] = M00 * Qm[0][0] + M01 * Qm[1][0] + M02 * Qm[2][0];
        A[0][1] = M00 * Qm[0][1] + M01 * Qm[1][1] + M02 * Qm[2][1];
        A[0][2] = M00 * Qm[0][2] + M01 * Qm[1][2] + M02 * Qm[2][2];
        A[1][0] = M11 * Qm[1][0] + M12 * Qm[2][0];
        A[1][1] = M11 * Qm[1][1] + M12 * Qm[2][1];
        A[1][2] = M11 * Qm[1][2] + M12 * Qm[2][2];
        A[2][0] = M22 * Qm[2][0];
        A[2][1] = M22 * Qm[2][1];
        A[2][2] = M22 * Qm[2][2];
        float nv[3][3];
#pragma unroll
        for (int r = 0; r < 3; r++)
#pragma unroll
            for (int cc = 0; cc < 3; cc++)
                nv[r][cc] = Vt[r][0] * Qm[0][cc] + Vt[r][1] * Qm[1][cc] + Vt[r][2] * Qm[2][cc];
#pragma unroll
        for (int r = 0; r < 3; r++)
#pragma unroll
            for (int cc = 0; cc < 3; cc++) Vt[r][cc] = nv[r][cc];
    }

    // pass B: z-column sum + abs-max
    float s2 = 0.f, mx01 = 0.f, mx2 = 0.f;
#pragma unroll
    for (int k = 0; k < K_; k++) {
        float4 Cv = cloud[bu[k] & 0x7FF];
        float ccx = Cv.x - px, ccy = Cv.y - py, ccz = Cv.z - pz;
        float d0 = ccx * Vt[0][0] + ccy * Vt[1][0] + ccz * Vt[2][0];
        float d1 = ccx * Vt[0][1] + ccy * Vt[1][1] + ccz * Vt[2][1];
        float d2 = ccx * Vt[0][2] + ccy * Vt[1][2] + ccz * Vt[2][2];
        s2 += d2;
        mx01 = fmaxf(mx01, fmaxf(fabsf(d0), fabsf(d1)));
        mx2  = fmaxf(mx2, fabsf(d2));
    }
    float sg = (s2 > 0.f) ? 1.f : ((s2 < 0.f) ? -1.f : 0.f);
    float mx = fmaxf(mx01, (sg == 0.f) ? 0.f : mx2);
    float hs = 0.5f / mx;

    // pass C: STATIC two-level select of this lane's 4 keys (bu stays in VGPRs)
    {
        int i = base + il;
        float4* row = (float4*)(dcn + (size_t)i * 48);
        bool od = (s & 1) != 0, hi = (s & 2) != 0;
        unsigned lo0 = od ? bu[4]  : bu[0],  hi0 = od ? bu[12] : bu[8];
        unsigned lo1 = od ? bu[5]  : bu[1],  hi1 = od ? bu[13] : bu[9];
        unsigned lo2 = od ? bu[6]  : bu[2],  hi2 = od ? bu[14] : bu[10];
        unsigned lo3 = od ? bu[7]  : bu[3],  hi3 = od ? bu[15] : bu[11];
        unsigned u0 = hi ? hi0 : lo0;
        unsigned u1 = hi ? hi1 : lo1;
        unsigned u2 = hi ? hi2 : lo2;
        unsigned u3 = hi ? hi3 : lo3;
        float v[12];
        float4 Cv;
        Cv = cloud[u0 & 0x7FF];
        {
            float ccx = Cv.x - px, ccy = Cv.y - py, ccz = Cv.z - pz;
            float d2 = (ccx * Vt[0][2] + ccy * Vt[1][2] + ccz * Vt[2][2]) * sg;
            v[0] = (ccx * Vt[0][0] + ccy * Vt[1][0] + ccz * Vt[2][0]) * hs + 0.5f;
            v[1] = (ccx * Vt[0][1] + ccy * Vt[1][1] + ccz * Vt[2][1]) * hs + 0.5f;
            v[2] = d2 * hs + 0.5f;
        }
        Cv = cloud[u1 & 0x7FF];
        {
            float ccx = Cv.x - px, ccy = Cv.y - py, ccz = Cv.z - pz;
            float d2 = (ccx * Vt[0][2] + ccy * Vt[1][2] + ccz * Vt[2][2]) * sg;
            v[3] = (ccx * Vt[0][0] + ccy * Vt[1][0] + ccz * Vt[2][0]) * hs + 0.5f;
            v[4] = (ccx * Vt[0][1] + ccy * Vt[1][1] + ccz * Vt[2][1]) * hs + 0.5f;
            v[5] = d2 * hs + 0.5f;
        }
        Cv = cloud[u2 & 0x7FF];
        {
            float ccx = Cv.x - px, ccy = Cv.y - py, ccz = Cv.z - pz;
            float d2 = (ccx * Vt[0][2] + ccy * Vt[1][2] + ccz * Vt[2][2]) * sg;
            v[6] = (ccx * Vt[0][0] + ccy * Vt[1][0] + ccz * Vt[2][0]) * hs + 0.5f;
            v[7] = (ccx * Vt[0][1] + ccy * Vt[1][1] + ccz * Vt[2][1]) * hs + 0.5f;
            v[8] = d2 * hs + 0.5f;
        }
        Cv = cloud[u3 & 0x7FF];
        {
            float ccx = Cv.x - px, ccy = Cv.y - py, ccz = Cv.z - pz;
            float d2 = (ccx * Vt[0][2] + ccy * Vt[1][2] + ccz * Vt[2][2]) * sg;
            v[9]  = (ccx * Vt[0][0] + ccy * Vt[1][0] + ccz * Vt[2][0]) * hs + 0.5f;
            v[10] = (ccx * Vt[0][1] + ccy * Vt[1][1] + ccz * Vt[2][1]) * hs + 0.5f;
            v[11] = d2 * hs + 0.5f;
        }
        row[s * 3 + 0] = make_float4(v[0], v[1], v[2], v[3]);
        row[s * 3 + 1] = make_float4(v[4], v[5], v[6], v[7]);
        row[s * 3 + 2] = make_float4(v[8], v[9], v[10], v[11]);
    }
}

// ---------- Kernel 2: trilinear spline gather + out_nondir + BN partials -----
// f16 EXPANDED corner table: exp_h[f][bb] holds the 8 corner values of base
// cell bb = i0 + 4*i1 + 16*i2 (i in [0,3]^3) for feature f, packed into 16 B.
// Per (point,k) the old 4x ds_read2_b32 (~24 cyc LDS issue, the kernel's
// bottleneck) become ONE ds_read_b128 (~12 cyc). Row stride 520 halves
// (1040 B = 65*16): 16B-aligned and shifts banks by 4 per f-row, so the
// wave's 64 reads at wave-uniform bb hit all 32 banks evenly (8 dwords/bank
// = bytes floor). f16 error ~1e-4 on out_nondir, systematic -> ~1e-3 at the
// output (margin: absmax 0.031 vs threshold 0.088).
__global__ __launch_bounds__(256) void spline_kernel(const float* __restrict__ dcn,
                                                     const float* __restrict__ w_spline,
                                                     const float* __restrict__ w_root,
                                                     const float* __restrict__ b_spline,
                                                     float* __restrict__ x,
                                                     float* __restrict__ partials) {
    __shared__ __half exp_h[F_ * 520];   // 66560 B
    __shared__ float red[4][64];
    for (int idx = threadIdx.x; idx < 64 * 64; idx += 256) {
        int f = idx & 63, bb = idx >> 6;
        int i0 = bb & 3, i1 = (bb >> 2) & 3, i2 = bb >> 4;
        const float* wp = w_spline + (i0 + 5 * i1 + 25 * i2) * 64 + f;
        __half2 h0 = __float22half2_rn(make_float2(wp[0 * 64],  wp[1 * 64]));
        __half2 h1 = __float22half2_rn(make_float2(wp[5 * 64],  wp[6 * 64]));
        __half2 h2 = __float22half2_rn(make_float2(wp[25 * 64], wp[26 * 64]));
        __half2 h3 = __float22half2_rn(make_float2(wp[30 * 64], wp[31 * 64]));
        __half2* dst = (__half2*)&exp_h[f * 520 + bb * 8];
        dst[0] = h0; dst[1] = h1; dst[2] = h2; dst[3] = h3;
    }
    __syncthreads();
    int wave = threadIdx.x >> 6, f = threadIdx.x & 63;
    const __half* exp_row = &exp_h[f * 520];
    float wr = w_root[f] + b_spline[f];
    float s1 = 0.f, s2 = 0.f;
    for (int p = 0; p < 16; p++) {
        int i = blockIdx.x * 64 + wave * 16 + p;
        const float4* row = (const float4*)(dcn + (size_t)i * 48);
        float pr[48];
#pragma unroll
        for (int m = 0; m < 12; m++) {
            float4 v = row[m];
            pr[m * 4 + 0] = v.x; pr[m * 4 + 1] = v.y;
            pr[m * 4 + 2] = v.z; pr[m * 4 + 3] = v.w;
        }
        float acc = 0.f;
#pragma unroll
        for (int k = 0; k < K_; k++) {
            float p0 = pr[k * 3 + 0] * 4.f;
            float p1 = pr[k * 3 + 1] * 4.f;
            float p2 = pr[k * 3 + 2] * 4.f;
            float i0 = __builtin_amdgcn_fmed3f(floorf(p0), 0.f, 3.f);
            float i1 = __builtin_amdgcn_fmed3f(floorf(p1), 0.f, 3.f);
            float i2 = __builtin_amdgcn_fmed3f(floorf(p2), 0.f, 3.f);
            float f0 = p0 - i0, f1 = p1 - i1, f2 = p2 - i2;
            float g0 = 1.f - f0, g1 = 1.f - f1, g2 = 1.f - f2;
            int bb = (int)fmaf(i2, 16.f, fmaf(i1, 4.f, i0));
            uint4 rv = *((const uint4*)(exp_row + bb * 8));   // ds_read_b128
            float2 cA = __half22float2(*(__half2*)&rv.x);     // corners +0,+1
            float2 cB = __half22float2(*(__half2*)&rv.y);     // +5,+6
            float2 cC = __half22float2(*(__half2*)&rv.z);     // +25,+26
            float2 cD = __half22float2(*(__half2*)&rv.w);     // +30,+31
            float Av = fmaf(f0, cA.y, g0 * cA.x);
            float Bv = fmaf(f0, cB.y, g0 * cB.x);
            float Cv = fmaf(f0, cC.y, g0 * cC.x);
            float Dv = fmaf(f0, cD.y, g0 * cD.x);
            float U = fmaf(f1, Bv, g1 * Av);
            float V = fmaf(f1, Dv, g1 * Cv);
            acc = fmaf(g2, U, acc);
            acc = fmaf(f2, V, acc);
        }
        float xv = acc * (1.f / 16.f) + wr;
        x[(size_t)i * 64 + f] = xv;
        s1 += xv; s2 += xv * xv;
    }
    red[wave][f] = s1; __syncthreads();
    if (threadIdx.x < 64)
        partials[blockIdx.x * 128 + f] = red[0][f] + red[1][f] + red[2][f] + red[3][f];
    __syncthreads();
    red[wave][f] = s2; __syncthreads();
    if (threadIdx.x < 64)
        partials[blockIdx.x * 128 + 64 + f] = red[0][f] + red[1][f] + red[2][f] + red[3][f];
}

// ----------------------- Kernel 3: BN stats finalize -------------------------
__global__ __launch_bounds__(256) void stats_kernel(const float* __restrict__ partials,
                                                    const float* __restrict__ gamma,
                                                    const float* __restrict__ beta,
                                                    float* __restrict__ stats) {
    __shared__ double red1[256], red2[256];
    int t = threadIdx.x;
    int f = t & 63, g = t >> 6;
    double a0 = 0, a1 = 0, a2 = 0, a3 = 0, q0 = 0, q1 = 0, q2 = 0, q3 = 0;
    for (int b2 = g; b2 < 1024; b2 += 16) {
        a0 += (double)partials[(b2     ) * 128 + f];
        q0 += (double)partials[(b2     ) * 128 + 64 + f];
        a1 += (double)partials[(b2 +  4) * 128 + f];
        q1 += (double)partials[(b2 +  4) * 128 + 64 + f];
        a2 += (double)partials[(b2 +  8) * 128 + f];
        q2 += (double)partials[(b2 +  8) * 128 + 64 + f];
        a3 += (double)partials[(b2 + 12) * 128 + f];
        q3 += (double)partials[(b2 + 12) * 128 + 64 + f];
    }
    red1[t] = (a0 + a1) + (a2 + a3);
    red2[t] = (q0 + q1) + (q2 + q3);
    __syncthreads();
    if (t < 64) {
        double S1 = red1[t] + red1[t + 64] + red1[t + 128] + red1[t + 192];
        double S2 = red2[t] + red2[t + 64] + red2[t + 128] + red2[t + 192];
        double mu = S1 / (double)N_;
        double var = S2 / (double)N_ - mu * mu;
        double scale = (double)gamma[t] / sqrt(var + (double)EPS_);
        double shift = (double)beta[t] - mu * scale;
        stats[t] = (float)scale;
        stats[64 + t] = (float)shift;
    }
}

// -------------- Kernel 4: sigmoid + per-batch-chunk partial pool -------------
__global__ __launch_bounds__(256) void pool_partial_kernel(const float* __restrict__ x,
                                                           const float* __restrict__ stats,
                                                           float* __restrict__ pp) {
    __shared__ float red[4][64];
    int blk = blockIdx.x;            // 32 batches * 32 chunks of 64 rows
    int b = blk >> 5, ch = blk & 31;
    int f = threadIdx.x & 63, w = threadIdx.x >> 6;
    float scale = stats[f], shift = stats[64 + f];
    float acc = 0.f;
    int row0 = b * P_ + ch * 64;
    for (int r = w; r < 64; r += 4) {
        float v = x[(size_t)(row0 + r) * 64 + f];
        float t = fmaf(v, scale, shift);
        acc += __fdividef(1.f, 1.f + __expf(-t));
    }
    red[w][f] = acc; __syncthreads();
    if (threadIdx.x < 64) pp[blk * 64 + f] = red[0][f] + red[1][f] + red[2][f] + red[3][f];
}

// --------- Kernel 5: batch means + GEMM1 + ELU + GEMM2 + log_softmax --------
__global__ __launch_bounds__(256) void mlp_kernel(const float* __restrict__ pp,
                                                  const float* __restrict__ w1,
                                                  const float* __restrict__ b1,
                                                  const float* __restrict__ w2,
                                                  const float* __restrict__ b2,
                                                  float* __restrict__ out) {
    __shared__ float ssy[64];
    __shared__ float sy1[256];
    int b = blockIdx.x, t = threadIdx.x;
    if (t < 64) {
        float s = 0.f;
#pragma unroll
        for (int g = 0; g < 32; g++) s += pp[(b * 32 + g) * 64 + t];
        ssy[t] = s * (1.f / 2048.f);
    }
    __syncthreads();
    {
        float acc = b1[t];
#pragma unroll 8
        for (int c = 0; c < F_; c++) acc = fmaf(ssy[c], w1[c * 256 + t], acc);
        sy1[t] = acc > 0.f ? acc : expm1f(acc);
    }
    __syncthreads();
    if (t < 64) {
        int j = t;
        float acc = -INFINITY;
        if (j < NC_) {
            acc = b2[j];
#pragma unroll 8
            for (int c = 0; c < H_; c++) acc = fmaf(sy1[c], w2[c * 40 + j], acc);
        }
        float m = acc;
#pragma unroll
        for (int o = 32; o > 0; o >>= 1) m = fmaxf(m, __shfl_xor(m, o, 64));
        float e = (j < NC_) ? expf(acc - m) : 0.f;
        float s = e;
#pragma unroll
        for (int o = 32; o > 0; o >>= 1) s += __shfl_xor(s, o, 64);
        if (j < NC_) out[b * NC_ + j] = acc - m - logf(s);
    }
}

extern "C" void kernel_launch(void* const* d_in, const int* in_sizes, int n_in,
                              void* d_out, int out_size, void* d_ws, size_t ws_size,
                              hipStream_t stream) {
    const float* pos      = (const float*)d_in[0];
    const float* w_spline = (const float*)d_in[2];
    const float* w_root   = (const float*)d_in[3];
    const float* b_spline = (const float*)d_in[4];
    const float* bn_gamma = (const float*)d_in[5];
    const float* bn_beta  = (const float*)d_in[6];
    const float* w1       = (const float*)d_in[7];
    const float* b1       = (const float*)d_in[8];
    const float* w2       = (const float*)d_in[9];
    const float* b2       = (const float*)d_in[10];
    float* out = (float*)d_out;

    char* ws = (char*)d_ws;
    float* dcn      = (float*)(ws + 0);                    // 12 MB
    float* x        = (float*)(ws + (12u << 20));          // 16 MB
    float* partials = (float*)(ws + (28u << 20));          // 512 KB
    float* stats    = (float*)(ws + (28u << 20) + (512u << 10));               // 4 KB slot
    float* pp       = (float*)(ws + (28u << 20) + (512u << 10) + 4096);        // 256 KB

    knn_geom_kernel<<<B_ * 32, 256, 0, stream>>>(pos, dcn);
    spline_kernel<<<N_ / 64, 256, 0, stream>>>(dcn, w_spline, w_root, b_spline, x, partials);
    stats_kernel<<<1, 256, 0, stream>>>(partials, bn_gamma, bn_beta, stats);
    pool_partial_kernel<<<B_ * 32, 256, 0, stream>>>(x, stats, pp);
    mlp_kernel<<<B_, 256, 0, stream>>>(pp, w1, b1, w2, b2, out);
}

// Round 18
// 204.214 us; speedup vs baseline: 1.0705x; 1.0705x over previous
//
#include <hip/hip_runtime.h>
#include <math.h>

#define B_ 32
#define P_ 2048
#define N_ 65536
#define K_ 16
#define L_ 8
#define F_ 64
#define KS_ 5
#define KS3_ 125
#define NC_ 40
#define H_ 256
#define EPS_ 1e-5f
#define QPB_ 64      // queries per block (knn)
#define SEG_ 4       // segment lanes per query (knn)

typedef _Float16 h2v __attribute__((ext_vector_type(2)));

__device__ __forceinline__ h2v u2h(unsigned u) { h2v h; __builtin_memcpy(&h, &u, 4); return h; }

// pack two f32 -> f16x2 (round toward zero) as a raw u32; memcpy-bitcast
// handles the __fp16x2 vs _Float16x2 type mismatch that broke round 17.
__device__ __forceinline__ unsigned pkrtz(float a, float b) {
    auto h = __builtin_amdgcn_cvt_pkrtz(a, b);
    unsigned u; __builtin_memcpy(&u, &h, 4); return u;
}

#if __has_builtin(__builtin_amdgcn_fdot2)
#define DOT2(a, b, c) __builtin_amdgcn_fdot2((a), (b), (c), false)
#else
__device__ __forceinline__ float DOT2(h2v a, h2v b, float c) {
    return fmaf((float)a[0], (float)b[0], fmaf((float)a[1], (float)b[1], c));
}
#endif

// exact same fp expression everywhere (pinned fmaf order)
__device__ __forceinline__ float distf(float4 C, float nx, float ny, float nz, float qs) {
    return fmaf(C.x, nx, fmaf(C.y, ny, fmaf(C.z, nz, C.w))) + qs;
}

// compare-exchange (ascending): 2 inst
#define CES(a, b) { unsigned _mn = min(a, b); b = max(a, b); a = _mn; }

// Batcher odd-even mergesort of 8 (19 CE)
__device__ __forceinline__ void sort8(unsigned& e0, unsigned& e1, unsigned& e2, unsigned& e3,
                                      unsigned& e4, unsigned& e5, unsigned& e6, unsigned& e7) {
    CES(e0, e1) CES(e2, e3) CES(e4, e5) CES(e6, e7)
    CES(e0, e2) CES(e1, e3) CES(e4, e6) CES(e5, e7)
    CES(e1, e2) CES(e5, e6)
    CES(e0, e4) CES(e1, e5) CES(e2, e6) CES(e3, e7)
    CES(e2, e4) CES(e3, e5)
    CES(e1, e2) CES(e3, e4) CES(e5, e6)
}

// ascending bitonic merge of a bitonic 16-sequence (32 CE, fully static)
__device__ __forceinline__ void bitmerge16(unsigned (&a)[16]) {
#pragma unroll
    for (int dd = 8; dd >= 1; dd >>= 1)
#pragma unroll
        for (int k2 = 0; k2 < 16; k2 += 2 * dd)
#pragma unroll
            for (int i2 = k2; i2 < k2 + dd; i2++)
                CES(a[i2], a[i2 + dd])
}

// full sort of 16 keys
__device__ __forceinline__ void sort16(unsigned (&a)[16]) {
    sort8(a[0], a[1], a[2], a[3], a[4], a[5], a[6], a[7]);
    sort8(a[8], a[9], a[10], a[11], a[12], a[13], a[14], a[15]);
    unsigned t;
    t = a[8];  a[8]  = a[15]; a[15] = t;
    t = a[9];  a[9]  = a[14]; a[14] = t;
    t = a[10]; a[10] = a[13]; a[13] = t;
    t = a[11]; a[11] = a[12]; a[12] = t;
    bitmerge16(a);
}

// Flush 8 buffered keys into sorted-ascending bu[16] (== 8 sorted-inserts)
__device__ __forceinline__ void flush8(unsigned (&bu)[16],
                                       unsigned& e0, unsigned& e1, unsigned& e2, unsigned& e3,
                                       unsigned& e4, unsigned& e5, unsigned& e6, unsigned& e7,
                                       unsigned& thr) {
    sort8(e0, e1, e2, e3, e4, e5, e6, e7);
    CES(bu[8],  e7) CES(bu[9],  e6) CES(bu[10], e5) CES(bu[11], e4)
    CES(bu[12], e3) CES(bu[13], e2) CES(bu[14], e1) CES(bu[15], e0)
    bitmerge16(bu);
    e0 = e1 = e2 = e3 = e4 = e5 = e6 = e7 = 0xFFFFFFFFu;
    unsigned t16 = bu[15];          // share threshold across the 4 seg-lanes
    t16 = min(t16, (unsigned)__shfl_xor((int)t16, 1, 64));
    t16 = min(t16, (unsigned)__shfl_xor((int)t16, 2, 64));
    thr = min(thr, t16);
}

// ---- Kernel 1: KNN + geometry (unchanged from round 15/16: 105 us) ----
__global__ __launch_bounds__(256, 2) void knn_geom_kernel(const float* __restrict__ pos,
                                                          float* __restrict__ dcn) {
    __shared__ float4 cloud[P_ + 8];             // 32 KB + pad
    int b = blockIdx.x >> 5, tile = blockIdx.x & 31;
    int base = b * P_;
    int t = threadIdx.x;
    for (int j = t; j < P_; j += 256) {
        float x = pos[(base + j) * 3 + 0];
        float y = pos[(base + j) * 3 + 1];
        float z = pos[(base + j) * 3 + 2];
        cloud[j] = make_float4(x, y, z, x * x + y * y + z * z);
    }
    if (t < 8) cloud[P_ + t] = make_float4(0.f, 0.f, 0.f, 1e30f);  // pad: huge d
    __syncthreads();

    int s = t & 3;                                // segment lane
    int il = tile * QPB_ + (t >> 2);              // this lane's query
    float4 Q = cloud[il];
    float nx = -2.f * Q.x, ny = -2.f * Q.y, nz = -2.f * Q.z, qs = Q.w;

    int j0 = s << 9, off = s << 1;

    // ---- warm-start: candidates [off, off+15] -> sorted bu, fresh thr ----
    unsigned bu[16];
#pragma unroll
    for (int m = 0; m < 16; m++) {
        int j_ = j0 + off + m;
        float4 Cv = cloud[j_];
        float d_ = distf(Cv, nx, ny, nz, qs);
        bu[m] = (__float_as_uint(fmaxf(d_, 0.f)) & 0xFFFFF800u) | (unsigned)j_;
    }
    sort16(bu);
    unsigned thr;
    {
        unsigned t16 = bu[15];
        t16 = min(t16, (unsigned)__shfl_xor((int)t16, 1, 64));
        t16 = min(t16, (unsigned)__shfl_xor((int)t16, 2, 64));
        thr = t16;
    }

    unsigned e0 = ~0u, e1 = ~0u, e2 = ~0u, e3 = ~0u,
             e4 = ~0u, e5 = ~0u, e6 = ~0u, e7 = ~0u;

#define VISITL(Cv, Jv) {                                                         \
        float d_ = distf(Cv, nx, ny, nz, qs);                                    \
        unsigned key_ = (__float_as_uint(fmaxf(d_, 0.f)) & 0xFFFFF800u)          \
                        | (unsigned)(Jv);                                        \
        bool a_ = (key_ < thr);                                                  \
        e7 = a_ ? e6 : e7;  e6 = a_ ? e5 : e6;  e5 = a_ ? e4 : e5;               \
        e4 = a_ ? e3 : e4;  e3 = a_ ? e2 : e3;  e2 = a_ ? e1 : e2;               \
        e1 = a_ ? e0 : e1;  e0 = a_ ? key_ : e0;                                 \
    }
#define VISITP(Cv, Jv, P) {                                                      \
        float d_ = distf(Cv, nx, ny, nz, qs);                                    \
        unsigned key_ = (__float_as_uint(fmaxf(d_, 0.f)) & 0xFFFFF800u)          \
                        | (unsigned)(Jv);                                        \
        bool a_ = (key_ < thr) && (P);                                           \
        e7 = a_ ? e6 : e7;  e6 = a_ ? e5 : e6;  e5 = a_ ? e4 : e5;               \
        e4 = a_ ? e3 : e4;  e3 = a_ ? e2 : e3;  e2 = a_ ? e1 : e2;               \
        e1 = a_ ? e0 : e1;  e0 = a_ ? key_ : e0;                                 \
    }

    // ---- main: 488 linear visits, jj in [off+16, off+503] ----
    const float4* cp = &cloud[j0 + off + 16];
    int jc = j0 + off + 16;
    for (int v = 0; v < 488; v += 4) {
        float4 a0 = cp[v + 0], a1 = cp[v + 1], a2 = cp[v + 2], a3 = cp[v + 3];
        VISITL(a0, jc + 0)
        VISITL(a1, jc + 1)
        VISITL(a2, jc + 2)
        VISITL(a3, jc + 3)
        jc += 4;
        if (__any(e4 != 0xFFFFFFFFu))
            flush8(bu, e0, e1, e2, e3, e4, e5, e6, e7, thr);
    }
    // ---- epilogue: v = 488..495, accept iff v < 496-off (pad reads masked) --
    {
        int vlim = 496 - off;
#pragma unroll
        for (int v = 488; v < 492; v++) {
            float4 a0 = cp[v];
            VISITP(a0, jc, v < vlim) jc++;
        }
        if (__any(e4 != 0xFFFFFFFFu))
            flush8(bu, e0, e1, e2, e3, e4, e5, e6, e7, thr);
#pragma unroll
        for (int v = 492; v < 496; v++) {
            float4 a0 = cp[v];
            VISITP(a0, jc, v < vlim) jc++;
        }
        if (__any(e4 != 0xFFFFFFFFu))
            flush8(bu, e0, e1, e2, e3, e4, e5, e6, e7, thr);
    }
    // ---- head tail: [0, off) ----
    {
#pragma unroll
        for (int u = 0; u < 4; u++) {
            float4 a0 = cloud[j0 + u];
            VISITP(a0, j0 + u, u < off)
        }
        if (__any(e4 != 0xFFFFFFFFu))
            flush8(bu, e0, e1, e2, e3, e4, e5, e6, e7, thr);
#pragma unroll
        for (int u = 4; u < 6; u++) {
            float4 a0 = cloud[j0 + u];
            VISITP(a0, j0 + u, u < off)
        }
    }
    flush8(bu, e0, e1, e2, e3, e4, e5, e6, e7, thr);   // drain
#undef VISITL
#undef VISITP

    // ---- self-removal: owner lane's bu[0] is self (global min key) ----
    {
        bool own = (s == (il >> 9));
#pragma unroll
        for (int m = 0; m < 15; m++) bu[m] = own ? bu[m + 1] : bu[m];
        bu[15] = own ? 0xFFFFFFFFu : bu[15];
    }

    // ---- 2 bitonic rounds: all 4 seg-lanes -> sorted union-top-16 ----
#pragma unroll
    for (int mask = 1; mask <= 2; mask <<= 1) {
        unsigned o[16];
#pragma unroll
        for (int i = 0; i < 16; i++)
            o[i] = (unsigned)__shfl_xor((int)bu[15 - i], mask, 64);  // partner reversed
#pragma unroll
        for (int i = 0; i < 16; i++) bu[i] = min(bu[i], o[i]);       // half-cleaner
        bitmerge16(bu);
    }

    // ---- geometry: cov over L=8, 5x QR (LAPACK Householder), dc ----
    float px = Q.x, py = Q.y, pz = Q.z;
    float A[3][3];
    {
        float a00 = 0, a01 = 0, a02 = 0, a11 = 0, a12 = 0, a22 = 0;
#pragma unroll
        for (int l = 0; l < L_; l++) {
            float4 Cv = cloud[bu[l] & 0x7FF];
            float ccx = Cv.x - px, ccy = Cv.y - py, ccz = Cv.z - pz;
            a00 += ccx * ccx; a01 += ccx * ccy; a02 += ccx * ccz;
            a11 += ccy * ccy; a12 += ccy * ccz; a22 += ccz * ccz;
        }
        A[0][0] = a00; A[0][1] = a01; A[0][2] = a02;
        A[1][0] = a01; A[1][1] = a11; A[1][2] = a12;
        A[2][0] = a02; A[2][1] = a12; A[2][2] = a22;
    }
    float Vt[3][3] = {{1.f, 0.f, 0.f}, {0.f, 1.f, 0.f}, {0.f, 0.f, 1.f}};

    for (int it = 0; it < 5; it++) {
        float M00 = A[0][0], M01 = A[0][1], M02 = A[0][2];
        float M10 = A[1][0], M11 = A[1][1], M12 = A[1][2];
        float M20 = A[2][0], M21 = A[2][1], M22 = A[2][2];
        float tau0 = 0.f, v1 = 0.f, v2 = 0.f;
        float xn2 = M10 * M10 + M20 * M20;
        if (xn2 != 0.f) {
            float beta = -copysignf(sqrtf(M00 * M00 + xn2), M00);
            tau0 = (beta - M00) / beta;
            float inv = 1.f / (M00 - beta);
            v1 = M10 * inv; v2 = M20 * inv;
            float sc;
            sc = tau0 * (M01 + v1 * M11 + v2 * M21); M01 -= sc; M11 -= v1 * sc; M21 -= v2 * sc;
            sc = tau0 * (M02 + v1 * M12 + v2 * M22); M02 -= sc; M12 -= v1 * sc; M22 -= v2 * sc;
            M00 = beta;
        }
        float tau1 = 0.f, u2 = 0.f;
        if (M21 != 0.f) {
            float beta1 = -copysignf(sqrtf(M11 * M11 + M21 * M21), M11);
            tau1 = (beta1 - M11) / beta1;
            u2 = M21 / (M11 - beta1);
            float sc = tau1 * (M12 + u2 * M22); M12 -= sc; M22 -= u2 * sc;
            M11 = beta1;
        }
        float h11 = 1.f - tau1, h12 = -tau1 * u2, h22 = 1.f - tau1 * u2 * u2;
        float Qm[3][3];
        Qm[0][0] = 1.f - tau0;
        Qm[1][0] = -v1 * tau0;
        Qm[2][0] = -v2 * tau0;
        float t1 = tau0 * (v1 * h11 + v2 * h12);
        Qm[0][1] = -t1;
        Qm[1][1] = h11 - v1 * t1;
        Qm[2][1] = h12 - v2 * t1;
        float t2 = tau0 * (v1 * h12 + v2 * h22);
        Qm[0][2] = -t2;
        Qm[1][2] = h12 - v1 * t2;
        Qm[2][2] = h22 - v2 * t2;
        A[0][0] = M00 * Qm[0][0] + M01 * Qm[1][0] + M02 * Qm[2][0];
        A[0][1] = M00 * Qm[0][1] + M01 * Qm[1][1] + M02 * Qm[2][1];
        A[0][2] = M00 * Qm[0][2] + M01 * Qm[1][2] + M02 * Qm[2][2];
        A[1][0] = M11 * Qm[1][0] + M12 * Qm[2][0];
        A[1][1] = M11 * Qm[1][1] + M12 * Qm[2][1];
        A[1][2] = M11 * Qm[1][2] + M12 * Qm[2][2];
        A[2][0] = M22 * Qm[2][0];
        A[2][1] = M22 * Qm[2][1];
        A[2][2] = M22 * Qm[2][2];
        float nv[3][3];
#pragma unroll
        for (int r = 0; r < 3; r++)
#pragma unroll
            for (int cc = 0; cc < 3; cc++)
                nv[r][cc] = Vt[r][0] * Qm[0][cc] + Vt[r][1] * Qm[1][cc] + Vt[r][2] * Qm[2][cc];
#pragma unroll
        for (int r = 0; r < 3; r++)
#pragma unroll
            for (int cc = 0; cc < 3; cc++) Vt[r][cc] = nv[r][cc];
    }

    // pass B: z-column sum + abs-max
    float s2 = 0.f, mx01 = 0.f, mx2 = 0.f;
#pragma unroll
    for (int k = 0; k < K_; k++) {
        float4 Cv = cloud[bu[k] & 0x7FF];
        float ccx = Cv.x - px, ccy = Cv.y - py, ccz = Cv.z - pz;
        float d0 = ccx * Vt[0][0] + ccy * Vt[1][0] + ccz * Vt[2][0];
        float d1 = ccx * Vt[0][1] + ccy * Vt[1][1] + ccz * Vt[2][1];
        float d2 = ccx * Vt[0][2] + ccy * Vt[1][2] + ccz * Vt[2][2];
        s2 += d2;
        mx01 = fmaxf(mx01, fmaxf(fabsf(d0), fabsf(d1)));
        mx2  = fmaxf(mx2, fabsf(d2));
    }
    float sg = (s2 > 0.f) ? 1.f : ((s2 < 0.f) ? -1.f : 0.f);
    float mx = fmaxf(mx01, (sg == 0.f) ? 0.f : mx2);
    float hs = 0.5f / mx;

    // pass C: STATIC two-level select of this lane's 4 keys (bu stays in VGPRs)
    {
        int i = base + il;
        float4* row = (float4*)(dcn + (size_t)i * 48);
        bool od = (s & 1) != 0, hi = (s & 2) != 0;
        unsigned lo0 = od ? bu[4]  : bu[0],  hi0 = od ? bu[12] : bu[8];
        unsigned lo1 = od ? bu[5]  : bu[1],  hi1 = od ? bu[13] : bu[9];
        unsigned lo2 = od ? bu[6]  : bu[2],  hi2 = od ? bu[14] : bu[10];
        unsigned lo3 = od ? bu[7]  : bu[3],  hi3 = od ? bu[15] : bu[11];
        unsigned u0 = hi ? hi0 : lo0;
        unsigned u1 = hi ? hi1 : lo1;
        unsigned u2 = hi ? hi2 : lo2;
        unsigned u3 = hi ? hi3 : lo3;
        float v[12];
        float4 Cv;
        Cv = cloud[u0 & 0x7FF];
        {
            float ccx = Cv.x - px, ccy = Cv.y - py, ccz = Cv.z - pz;
            float d2 = (ccx * Vt[0][2] + ccy * Vt[1][2] + ccz * Vt[2][2]) * sg;
            v[0] = (ccx * Vt[0][0] + ccy * Vt[1][0] + ccz * Vt[2][0]) * hs + 0.5f;
            v[1] = (ccx * Vt[0][1] + ccy * Vt[1][1] + ccz * Vt[2][1]) * hs + 0.5f;
            v[2] = d2 * hs + 0.5f;
        }
        Cv = cloud[u1 & 0x7FF];
        {
            float ccx = Cv.x - px, ccy = Cv.y - py, ccz = Cv.z - pz;
            float d2 = (ccx * Vt[0][2] + ccy * Vt[1][2] + ccz * Vt[2][2]) * sg;
            v[3] = (ccx * Vt[0][0] + ccy * Vt[1][0] + ccz * Vt[2][0]) * hs + 0.5f;
            v[4] = (ccx * Vt[0][1] + ccy * Vt[1][1] + ccz * Vt[2][1]) * hs + 0.5f;
            v[5] = d2 * hs + 0.5f;
        }
        Cv = cloud[u2 & 0x7FF];
        {
            float ccx = Cv.x - px, ccy = Cv.y - py, ccz = Cv.z - pz;
            float d2 = (ccx * Vt[0][2] + ccy * Vt[1][2] + ccz * Vt[2][2]) * sg;
            v[6] = (ccx * Vt[0][0] + ccy * Vt[1][0] + ccz * Vt[2][0]) * hs + 0.5f;
            v[7] = (ccx * Vt[0][1] + ccy * Vt[1][1] + ccz * Vt[2][1]) * hs + 0.5f;
            v[8] = d2 * hs + 0.5f;
        }
        Cv = cloud[u3 & 0x7FF];
        {
            float ccx = Cv.x - px, ccy = Cv.y - py, ccz = Cv.z - pz;
            float d2 = (ccx * Vt[0][2] + ccy * Vt[1][2] + ccz * Vt[2][2]) * sg;
            v[9]  = (ccx * Vt[0][0] + ccy * Vt[1][0] + ccz * Vt[2][0]) * hs + 0.5f;
            v[10] = (ccx * Vt[0][1] + ccy * Vt[1][1] + ccz * Vt[2][1]) * hs + 0.5f;
            v[11] = d2 * hs + 0.5f;
        }
        row[s * 3 + 0] = make_float4(v[0], v[1], v[2], v[3]);
        row[s * 3 + 1] = make_float4(v[4], v[5], v[6], v[7]);
        row[s * 3 + 2] = make_float4(v[8], v[9], v[10], v[11]);
    }
}

// ---------- Kernel 2: spline as coeff-GEMM ----------
// out[64pts x 64f] = Coeff[64 x 128cells] * W[128cells x 64f]
// Phase 1 (lane = point, 4 threads/pt split k): trilinear weights computed
// ONCE per point (previously recomputed identically by all 64 lanes of a
// wave = 64x redundant issue) and scatter-added into LDS Coeff32 via
// atomicAdd (cells <= 124 < 128; banks spread by random cell).
// Phase 2/3: Coeff32 -> f16 pairs, ALIASED into the Coeff32 region
// (stage-to-regs + barriers) -> total LDS 49 KB = 3 blocks/CU (r16's 2-block
// occupancy regression avoided). Phase 4 (lane = f): Wt row hoisted to 64
// VGPRs, per point 16 broadcast b128 coeff reads + 64 fdot2 (4 acc chains).
// f16 table proven safe in r16 (absmax unchanged 0.03125); coeff f16 adds
// ~5e-4 rel. LDS-atomic add order varies run-to-run at ~1e-7 (harness
// re-validates vs reference threshold 8.8e-2, not bitwise).
__global__ __launch_bounds__(256) void spline_kernel(const float* __restrict__ dcn,
                                                     const float* __restrict__ w_spline,
                                                     const float* __restrict__ w_root,
                                                     const float* __restrict__ b_spline,
                                                     float* __restrict__ x,
                                                     float* __restrict__ partials) {
    __shared__ float C32[64 * 128];      // 32 KB; low 16 KB later reused as C16
    __shared__ unsigned Wt2[64 * 64];    // 16 KB, [cc][f] packed half2 (cells 2cc,2cc+1)
    __shared__ float red[4][64];
    int t = threadIdx.x;
    int base_i = blockIdx.x * 64;

    // phase 0: zero Coeff32 + build Wt2
    {
        float4 z = make_float4(0.f, 0.f, 0.f, 0.f);
        float4* c4 = (float4*)C32;
#pragma unroll
        for (int r = 0; r < 8; r++) c4[t + r * 256] = z;
    }
    for (int idx = t; idx < 64 * 64; idx += 256) {
        int f = idx & 63, cc = idx >> 6;
        float w0 = (2 * cc < KS3_) ? w_spline[(2 * cc) * 64 + f] : 0.f;
        float w1 = (2 * cc + 1 < KS3_) ? w_spline[(2 * cc + 1) * 64 + f] : 0.f;
        Wt2[idx] = pkrtz(w0, w1);
    }
    __syncthreads();

    // phase 1: build coefficients. thread t: point p = t&63, k-group kg = t>>6
    {
        int p = t & 63, kg = t >> 6;
        const float4* dr = (const float4*)(dcn + (size_t)(base_i + p) * 48) + kg * 3;
        float4 fa = dr[0], fb = dr[1], fc = dr[2];
        float* crow = &C32[p * 128];
        float sx[12] = {fa.x, fa.y, fa.z, fa.w, fb.x, fb.y, fb.z, fb.w, fc.x, fc.y, fc.z, fc.w};
#pragma unroll
        for (int q = 0; q < 4; q++) {
            float p0 = sx[q * 3 + 0] * 4.f;
            float p1 = sx[q * 3 + 1] * 4.f;
            float p2 = sx[q * 3 + 2] * 4.f;
            float i0 = fminf(floorf(p0), 3.f);
            float i1 = fminf(floorf(p1), 3.f);
            float i2 = fminf(floorf(p2), 3.f);
            float f0 = p0 - i0, f1 = p1 - i1, f2 = p2 - i2;
            float g0 = 1.f - f0, g1 = 1.f - f1, g2 = 1.f - f2;
            int c = (int)fmaf(i2, 25.f, fmaf(i1, 5.f, i0));
            float wA = g1 * g2, wB = f1 * g2, wC = g1 * f2, wD = f1 * f2;
            atomicAdd(&crow[c + 0],  g0 * wA);
            atomicAdd(&crow[c + 1],  f0 * wA);
            atomicAdd(&crow[c + 5],  g0 * wB);
            atomicAdd(&crow[c + 6],  f0 * wB);
            atomicAdd(&crow[c + 25], g0 * wC);
            atomicAdd(&crow[c + 26], f0 * wC);
            atomicAdd(&crow[c + 30], g0 * wD);
            atomicAdd(&crow[c + 31], f0 * wD);
        }
    }
    __syncthreads();

    // phase 2: stage this thread's 32 f32 coeffs (point t>>2, cc window (t&3)*32)
    float st[32];
    {
        int p = t >> 2, w4 = t & 3;
        const float4* src = (const float4*)&C32[p * 128] + w4 * 8;
#pragma unroll
        for (int r = 0; r < 8; r++) {
            float4 v = src[r];
            st[r * 4 + 0] = v.x; st[r * 4 + 1] = v.y;
            st[r * 4 + 2] = v.z; st[r * 4 + 3] = v.w;
        }
    }
    __syncthreads();
    // phase 3: write f16 pairs into C16 (aliases low 16 KB of C32)
    {
        int p = t >> 2, w4 = t & 3;
        uint4* dst = (uint4*)C32 + p * 16 + w4 * 4;
#pragma unroll
        for (int r = 0; r < 4; r++) {
            uint4 pk;
            pk.x = pkrtz(st[r * 8 + 0], st[r * 8 + 1]);
            pk.y = pkrtz(st[r * 8 + 2], st[r * 8 + 3]);
            pk.z = pkrtz(st[r * 8 + 4], st[r * 8 + 5]);
            pk.w = pkrtz(st[r * 8 + 6], st[r * 8 + 7]);
            dst[r] = pk;
        }
    }
    __syncthreads();

    // phase 4: contraction. wave = point stripe, lane = f.
    {
        int wave = t >> 6, f = t & 63;
        float wr = w_root[f] + b_spline[f];
        h2v wreg[64];
#pragma unroll
        for (int cc = 0; cc < 64; cc++) wreg[cc] = u2h(Wt2[cc * 64 + f]);
        const uint4* C16q = (const uint4*)C32;
        float s1 = 0.f, s2sum = 0.f;
        for (int pp = 0; pp < 16; pp++) {
            int p = wave * 16 + pp;
            float a0 = 0.f, a1 = 0.f, a2 = 0.f, a3 = 0.f;
#pragma unroll
            for (int ch = 0; ch < 16; ch++) {
                uint4 rv = C16q[p * 16 + ch];
                a0 = DOT2(u2h(rv.x), wreg[ch * 4 + 0], a0);
                a1 = DOT2(u2h(rv.y), wreg[ch * 4 + 1], a1);
                a2 = DOT2(u2h(rv.z), wreg[ch * 4 + 2], a2);
                a3 = DOT2(u2h(rv.w), wreg[ch * 4 + 3], a3);
            }
            float xv = ((a0 + a1) + (a2 + a3)) * (1.f / 16.f) + wr;
            x[(size_t)(base_i + p) * 64 + f] = xv;
            s1 += xv; s2sum += xv * xv;
        }
        red[wave][f] = s1; __syncthreads();
        if (t < 64)
            partials[blockIdx.x * 128 + f] = red[0][f] + red[1][f] + red[2][f] + red[3][f];
        __syncthreads();
        red[wave][f] = s2sum; __syncthreads();
        if (t < 64)
            partials[blockIdx.x * 128 + 64 + f] = red[0][f] + red[1][f] + red[2][f] + red[3][f];
    }
}

// ----------------------- Kernel 3: BN stats finalize -------------------------
__global__ __launch_bounds__(256) void stats_kernel(const float* __restrict__ partials,
                                                    const float* __restrict__ gamma,
                                                    const float* __restrict__ beta,
                                                    float* __restrict__ stats) {
    __shared__ double red1[256], red2[256];
    int t = threadIdx.x;
    int f = t & 63, g = t >> 6;
    double a0 = 0, a1 = 0, a2 = 0, a3 = 0, q0 = 0, q1 = 0, q2 = 0, q3 = 0;
    for (int b2 = g; b2 < 1024; b2 += 16) {
        a0 += (double)partials[(b2     ) * 128 + f];
        q0 += (double)partials[(b2     ) * 128 + 64 + f];
        a1 += (double)partials[(b2 +  4) * 128 + f];
        q1 += (double)partials[(b2 +  4) * 128 + 64 + f];
        a2 += (double)partials[(b2 +  8) * 128 + f];
        q2 += (double)partials[(b2 +  8) * 128 + 64 + f];
        a3 += (double)partials[(b2 + 12) * 128 + f];
        q3 += (double)partials[(b2 + 12) * 128 + 64 + f];
    }
    red1[t] = (a0 + a1) + (a2 + a3);
    red2[t] = (q0 + q1) + (q2 + q3);
    __syncthreads();
    if (t < 64) {
        double S1 = red1[t] + red1[t + 64] + red1[t + 128] + red1[t + 192];
        double S2 = red2[t] + red2[t + 64] + red2[t + 128] + red2[t + 192];
        double mu = S1 / (double)N_;
        double var = S2 / (double)N_ - mu * mu;
        double scale = (double)gamma[t] / sqrt(var + (double)EPS_);
        double shift = (double)beta[t] - mu * scale;
        stats[t] = (float)scale;
        stats[64 + t] = (float)shift;
    }
}

// -------------- Kernel 4: sigmoid + per-batch-chunk partial pool -------------
__global__ __launch_bounds__(256) void pool_partial_kernel(const float* __restrict__ x,
                                                           const float* __restrict__ stats,
                                                           float* __restrict__ pp) {
    __shared__ float red[4][64];
    int blk = blockIdx.x;            // 32 batches * 32 chunks of 64 rows
    int b = blk >> 5, ch = blk & 31;
    int f = threadIdx.x & 63, w = threadIdx.x >> 6;
    float scale = stats[f], shift = stats[64 + f];
    float acc = 0.f;
    int row0 = b * P_ + ch * 64;
    for (int r = w; r < 64; r += 4) {
        float v = x[(size_t)(row0 + r) * 64 + f];
        float t = fmaf(v, scale, shift);
        acc += __fdividef(1.f, 1.f + __expf(-t));
    }
    red[w][f] = acc; __syncthreads();
    if (threadIdx.x < 64) pp[blk * 64 + f] = red[0][f] + red[1][f] + red[2][f] + red[3][f];
}

// --------- Kernel 5: batch means + GEMM1 + ELU + GEMM2 + log_softmax --------
__global__ __launch_bounds__(256) void mlp_kernel(const float* __restrict__ pp,
                                                  const float* __restrict__ w1,
                                                  const float* __restrict__ b1,
                                                  const float* __restrict__ w2,
                                                  const float* __restrict__ b2,
                                                  float* __restrict__ out) {
    __shared__ float ssy[64];
    __shared__ float sy1[256];
    int b = blockIdx.x, t = threadIdx.x;
    if (t < 64) {
        float s = 0.f;
#pragma unroll
        for (int g = 0; g < 32; g++) s += pp[(b * 32 + g) * 64 + t];
        ssy[t] = s * (1.f / 2048.f);
    }
    __syncthreads();
    {
        float acc = b1[t];
#pragma unroll 8
        for (int c = 0; c < F_; c++) acc = fmaf(ssy[c], w1[c * 256 + t], acc);
        sy1[t] = acc > 0.f ? acc : expm1f(acc);
    }
    __syncthreads();
    if (t < 64) {
        int j = t;
        float acc = -INFINITY;
        if (j < NC_) {
            acc = b2[j];
#pragma unroll 8
            for (int c = 0; c < H_; c++) acc = fmaf(sy1[c], w2[c * 40 + j], acc);
        }
        float m = acc;
#pragma unroll
        for (int o = 32; o > 0; o >>= 1) m = fmaxf(m, __shfl_xor(m, o, 64));
        float e = (j < NC_) ? expf(acc - m) : 0.f;
        float s = e;
#pragma unroll
        for (int o = 32; o > 0; o >>= 1) s += __shfl_xor(s, o, 64);
        if (j < NC_) out[b * NC_ + j] = acc - m - logf(s);
    }
}

extern "C" void kernel_launch(void* const* d_in, const int* in_sizes, int n_in,
                              void* d_out, int out_size, void* d_ws, size_t ws_size,
                              hipStream_t stream) {
    const float* pos      = (const float*)d_in[0];
    const float* w_spline = (const float*)d_in[2];
    const float* w_root   = (const float*)d_in[3];
    const float* b_spline = (const float*)d_in[4];
    const float* bn_gamma = (const float*)d_in[5];
    const float* bn_beta  = (const float*)d_in[6];
    const float* w1       = (const float*)d_in[7];
    const float* b1       = (const float*)d_in[8];
    const float* w2       = (const float*)d_in[9];
    const float* b2       = (const float*)d_in[10];
    float* out = (float*)d_out;

    char* ws = (char*)d_ws;
    float* dcn      = (float*)(ws + 0);                    // 12 MB
    float* x        = (float*)(ws + (12u << 20));          // 16 MB
    float* partials = (float*)(ws + (28u << 20));          // 512 KB
    float* stats    = (float*)(ws + (28u << 20) + (512u << 10));               // 4 KB slot
    float* pp       = (float*)(ws + (28u << 20) + (512u << 10) + 4096);        // 256 KB

    knn_geom_kernel<<<B_ * 32, 256, 0, stream>>>(pos, dcn);
    spline_kernel<<<N_ / 64, 256, 0, stream>>>(dcn, w_spline, w_root, b_spline, x, partials);
    stats_kernel<<<1, 256, 0, stream>>>(partials, bn_gamma, bn_beta, stats);
    pool_partial_kernel<<<B_ * 32, 256, 0, stream>>>(x, stats, pp);
    mlp_kernel<<<B_, 256, 0, stream>>>(pp, w1, b1, w2, b2, out);
}

// Round 19
// 189.804 us; speedup vs baseline: 1.1518x; 1.0759x over previous
//
#include <hip/hip_runtime.h>
#include <math.h>

#define B_ 32
#define P_ 2048
#define N_ 65536
#define K_ 16
#define L_ 8
#define F_ 64
#define KS_ 5
#define KS3_ 125
#define NC_ 40
#define H_ 256
#define EPS_ 1e-5f
#define QPB_ 128     // queries per block (knn; 512-thread blocks)
#define SEG_ 4       // segment lanes per query (knn)

// exact same fp expression everywhere (pinned fmaf order)
__device__ __forceinline__ float distf(float4 C, float nx, float ny, float nz, float qs) {
    return fmaf(C.x, nx, fmaf(C.y, ny, fmaf(C.z, nz, C.w))) + qs;
}

// compare-exchange (ascending): 2 inst
#define CES(a, b) { unsigned _mn = min(a, b); b = max(a, b); a = _mn; }

// Batcher odd-even mergesort of 8 (19 CE)
__device__ __forceinline__ void sort8(unsigned& e0, unsigned& e1, unsigned& e2, unsigned& e3,
                                      unsigned& e4, unsigned& e5, unsigned& e6, unsigned& e7) {
    CES(e0, e1) CES(e2, e3) CES(e4, e5) CES(e6, e7)
    CES(e0, e2) CES(e1, e3) CES(e4, e6) CES(e5, e7)
    CES(e1, e2) CES(e5, e6)
    CES(e0, e4) CES(e1, e5) CES(e2, e6) CES(e3, e7)
    CES(e2, e4) CES(e3, e5)
    CES(e1, e2) CES(e3, e4) CES(e5, e6)
}

// ascending bitonic merge of a bitonic 16-sequence (32 CE, fully static)
__device__ __forceinline__ void bitmerge16(unsigned (&a)[16]) {
#pragma unroll
    for (int dd = 8; dd >= 1; dd >>= 1)
#pragma unroll
        for (int k2 = 0; k2 < 16; k2 += 2 * dd)
#pragma unroll
            for (int i2 = k2; i2 < k2 + dd; i2++)
                CES(a[i2], a[i2 + dd])
}

// full sort of 16 keys
__device__ __forceinline__ void sort16(unsigned (&a)[16]) {
    sort8(a[0], a[1], a[2], a[3], a[4], a[5], a[6], a[7]);
    sort8(a[8], a[9], a[10], a[11], a[12], a[13], a[14], a[15]);
    unsigned t;
    t = a[8];  a[8]  = a[15]; a[15] = t;
    t = a[9];  a[9]  = a[14]; a[14] = t;
    t = a[10]; a[10] = a[13]; a[13] = t;
    t = a[11]; a[11] = a[12]; a[12] = t;
    bitmerge16(a);
}

// Flush 8 buffered keys into sorted-ascending bu[16] (== 8 sorted-inserts)
__device__ __forceinline__ void flush8(unsigned (&bu)[16],
                                       unsigned& e0, unsigned& e1, unsigned& e2, unsigned& e3,
                                       unsigned& e4, unsigned& e5, unsigned& e6, unsigned& e7,
                                       unsigned& thr) {
    sort8(e0, e1, e2, e3, e4, e5, e6, e7);
    CES(bu[8],  e7) CES(bu[9],  e6) CES(bu[10], e5) CES(bu[11], e4)
    CES(bu[12], e3) CES(bu[13], e2) CES(bu[14], e1) CES(bu[15], e0)
    bitmerge16(bu);
    e0 = e1 = e2 = e3 = e4 = e5 = e6 = e7 = 0xFFFFFFFFu;
    unsigned t16 = bu[15];          // share threshold across the 4 seg-lanes
    t16 = min(t16, (unsigned)__shfl_xor((int)t16, 1, 64));
    t16 = min(t16, (unsigned)__shfl_xor((int)t16, 2, 64));
    thr = min(thr, t16);
}

// ---- Kernel 1: KNN + geometry ----
// Same per-wave algorithm as round 15 (linear scan, warm-start, Batcher
// flush, 2-round bitonic union merge, static pass-C select). REGROUPED to
// 512-thread blocks (128 queries/block, 512 blocks): identical work, same
// 32.5 KB LDS, but if the residency limit is block-count-based (occupancy
// counter stuck at ~2 blocks/CU = 24% across r12-r18), this doubles
// waves/CU -> VALU issue slots currently idle (16%) get filled.
__global__ __launch_bounds__(512, 2) void knn_geom_kernel(const float* __restrict__ pos,
                                                          float* __restrict__ dcn) {
    __shared__ float4 cloud[P_ + 8];             // 32 KB + pad
    int b = blockIdx.x >> 4, tile = blockIdx.x & 15;
    int base = b * P_;
    int t = threadIdx.x;
    for (int j = t; j < P_; j += 512) {
        float x = pos[(base + j) * 3 + 0];
        float y = pos[(base + j) * 3 + 1];
        float z = pos[(base + j) * 3 + 2];
        cloud[j] = make_float4(x, y, z, x * x + y * y + z * z);
    }
    if (t < 8) cloud[P_ + t] = make_float4(0.f, 0.f, 0.f, 1e30f);  // pad: huge d
    __syncthreads();

    int s = t & 3;                                // segment lane
    int il = tile * QPB_ + (t >> 2);              // this lane's query
    float4 Q = cloud[il];
    float nx = -2.f * Q.x, ny = -2.f * Q.y, nz = -2.f * Q.z, qs = Q.w;

    int j0 = s << 9, off = s << 1;

    // ---- warm-start: candidates [off, off+15] -> sorted bu, fresh thr ----
    unsigned bu[16];
#pragma unroll
    for (int m = 0; m < 16; m++) {
        int j_ = j0 + off + m;
        float4 Cv = cloud[j_];
        float d_ = distf(Cv, nx, ny, nz, qs);
        bu[m] = (__float_as_uint(fmaxf(d_, 0.f)) & 0xFFFFF800u) | (unsigned)j_;
    }
    sort16(bu);
    unsigned thr;
    {
        unsigned t16 = bu[15];
        t16 = min(t16, (unsigned)__shfl_xor((int)t16, 1, 64));
        t16 = min(t16, (unsigned)__shfl_xor((int)t16, 2, 64));
        thr = t16;
    }

    unsigned e0 = ~0u, e1 = ~0u, e2 = ~0u, e3 = ~0u,
             e4 = ~0u, e5 = ~0u, e6 = ~0u, e7 = ~0u;

#define VISITL(Cv, Jv) {                                                         \
        float d_ = distf(Cv, nx, ny, nz, qs);                                    \
        unsigned key_ = (__float_as_uint(fmaxf(d_, 0.f)) & 0xFFFFF800u)          \
                        | (unsigned)(Jv);                                        \
        bool a_ = (key_ < thr);                                                  \
        e7 = a_ ? e6 : e7;  e6 = a_ ? e5 : e6;  e5 = a_ ? e4 : e5;               \
        e4 = a_ ? e3 : e4;  e3 = a_ ? e2 : e3;  e2 = a_ ? e1 : e2;               \
        e1 = a_ ? e0 : e1;  e0 = a_ ? key_ : e0;                                 \
    }
#define VISITP(Cv, Jv, P) {                                                      \
        float d_ = distf(Cv, nx, ny, nz, qs);                                    \
        unsigned key_ = (__float_as_uint(fmaxf(d_, 0.f)) & 0xFFFFF800u)          \
                        | (unsigned)(Jv);                                        \
        bool a_ = (key_ < thr) && (P);                                           \
        e7 = a_ ? e6 : e7;  e6 = a_ ? e5 : e6;  e5 = a_ ? e4 : e5;               \
        e4 = a_ ? e3 : e4;  e3 = a_ ? e2 : e3;  e2 = a_ ? e1 : e2;               \
        e1 = a_ ? e0 : e1;  e0 = a_ ? key_ : e0;                                 \
    }

    // ---- main: 488 linear visits, jj in [off+16, off+503] ----
    const float4* cp = &cloud[j0 + off + 16];
    int jc = j0 + off + 16;
    for (int v = 0; v < 488; v += 4) {
        float4 a0 = cp[v + 0], a1 = cp[v + 1], a2 = cp[v + 2], a3 = cp[v + 3];
        VISITL(a0, jc + 0)
        VISITL(a1, jc + 1)
        VISITL(a2, jc + 2)
        VISITL(a3, jc + 3)
        jc += 4;
        if (__any(e4 != 0xFFFFFFFFu))
            flush8(bu, e0, e1, e2, e3, e4, e5, e6, e7, thr);
    }
    // ---- epilogue: v = 488..495, accept iff v < 496-off (pad reads masked) --
    {
        int vlim = 496 - off;
#pragma unroll
        for (int v = 488; v < 492; v++) {
            float4 a0 = cp[v];
            VISITP(a0, jc, v < vlim) jc++;
        }
        if (__any(e4 != 0xFFFFFFFFu))
            flush8(bu, e0, e1, e2, e3, e4, e5, e6, e7, thr);
#pragma unroll
        for (int v = 492; v < 496; v++) {
            float4 a0 = cp[v];
            VISITP(a0, jc, v < vlim) jc++;
        }
        if (__any(e4 != 0xFFFFFFFFu))
            flush8(bu, e0, e1, e2, e3, e4, e5, e6, e7, thr);
    }
    // ---- head tail: [0, off) ----
    {
#pragma unroll
        for (int u = 0; u < 4; u++) {
            float4 a0 = cloud[j0 + u];
            VISITP(a0, j0 + u, u < off)
        }
        if (__any(e4 != 0xFFFFFFFFu))
            flush8(bu, e0, e1, e2, e3, e4, e5, e6, e7, thr);
#pragma unroll
        for (int u = 4; u < 6; u++) {
            float4 a0 = cloud[j0 + u];
            VISITP(a0, j0 + u, u < off)
        }
    }
    flush8(bu, e0, e1, e2, e3, e4, e5, e6, e7, thr);   // drain
#undef VISITL
#undef VISITP

    // ---- self-removal: owner lane's bu[0] is self (global min key) ----
    {
        bool own = (s == (il >> 9));
#pragma unroll
        for (int m = 0; m < 15; m++) bu[m] = own ? bu[m + 1] : bu[m];
        bu[15] = own ? 0xFFFFFFFFu : bu[15];
    }

    // ---- 2 bitonic rounds: all 4 seg-lanes -> sorted union-top-16 ----
#pragma unroll
    for (int mask = 1; mask <= 2; mask <<= 1) {
        unsigned o[16];
#pragma unroll
        for (int i = 0; i < 16; i++)
            o[i] = (unsigned)__shfl_xor((int)bu[15 - i], mask, 64);  // partner reversed
#pragma unroll
        for (int i = 0; i < 16; i++) bu[i] = min(bu[i], o[i]);       // half-cleaner
        bitmerge16(bu);
    }

    // ---- geometry: cov over L=8, 5x QR (LAPACK Householder), dc ----
    float px = Q.x, py = Q.y, pz = Q.z;
    float A[3][3];
    {
        float a00 = 0, a01 = 0, a02 = 0, a11 = 0, a12 = 0, a22 = 0;
#pragma unroll
        for (int l = 0; l < L_; l++) {
            float4 Cv = cloud[bu[l] & 0x7FF];
            float ccx = Cv.x - px, ccy = Cv.y - py, ccz = Cv.z - pz;
            a00 += ccx * ccx; a01 += ccx * ccy; a02 += ccx * ccz;
            a11 += ccy * ccy; a12 += ccy * ccz; a22 += ccz * ccz;
        }
        A[0][0] = a00; A[0][1] = a01; A[0][2] = a02;
        A[1][0] = a01; A[1][1] = a11; A[1][2] = a12;
        A[2][0] = a02; A[2][1] = a12; A[2][2] = a22;
    }
    float Vt[3][3] = {{1.f, 0.f, 0.f}, {0.f, 1.f, 0.f}, {0.f, 0.f, 1.f}};

    for (int it = 0; it < 5; it++) {
        float M00 = A[0][0], M01 = A[0][1], M02 = A[0][2];
        float M10 = A[1][0], M11 = A[1][1], M12 = A[1][2];
        float M20 = A[2][0], M21 = A[2][1], M22 = A[2][2];
        float tau0 = 0.f, v1 = 0.f, v2 = 0.f;
        float xn2 = M10 * M10 + M20 * M20;
        if (xn2 != 0.f) {
            float beta = -copysignf(sqrtf(M00 * M00 + xn2), M00);
            tau0 = (beta - M00) / beta;
            float inv = 1.f / (M00 - beta);
            v1 = M10 * inv; v2 = M20 * inv;
            float sc;
            sc = tau0 * (M01 + v1 * M11 + v2 * M21); M01 -= sc; M11 -= v1 * sc; M21 -= v2 * sc;
            sc = tau0 * (M02 + v1 * M12 + v2 * M22); M02 -= sc; M12 -= v1 * sc; M22 -= v2 * sc;
            M00 = beta;
        }
        float tau1 = 0.f, u2 = 0.f;
        if (M21 != 0.f) {
            float beta1 = -copysignf(sqrtf(M11 * M11 + M21 * M21), M11);
            tau1 = (beta1 - M11) / beta1;
            u2 = M21 / (M11 - beta1);
            float sc = tau1 * (M12 + u2 * M22); M12 -= sc; M22 -= u2 * sc;
            M11 = beta1;
        }
        float h11 = 1.f - tau1, h12 = -tau1 * u2, h22 = 1.f - tau1 * u2 * u2;
        float Qm[3][3];
        Qm[0][0] = 1.f - tau0;
        Qm[1][0] = -v1 * tau0;
        Qm[2][0] = -v2 * tau0;
        float t1 = tau0 * (v1 * h11 + v2 * h12);
        Qm[0][1] = -t1;
        Qm[1][1] = h11 - v1 * t1;
        Qm[2][1] = h12 - v2 * t1;
        float t2 = tau0 * (v1 * h12 + v2 * h22);
        Qm[0][2] = -t2;
        Qm[1][2] = h12 - v1 * t2;
        Qm[2][2] = h22 - v2 * t2;
        A[0][0] = M00 * Qm[0][0] + M01 * Qm[1][0] + M02 * Qm[2][0];
        A[0][1] = M00 * Qm[0][1] + M01 * Qm[1][1] + M02 * Qm[2][1];
        A[0][2] = M00 * Qm[0][2] + M01 * Qm[1][2] + M02 * Qm[2][2];
        A[1][0] = M11 * Qm[1][0] + M12 * Qm[2][0];
        A[1][1] = M11 * Qm[1][1] + M12 * Qm[2][1];
        A[1][2] = M11 * Qm[1][2] + M12 * Qm[2][2];
        A[2][0] = M22 * Qm[2][0];
        A[2][1] = M22 * Qm[2][1];
        A[2][2] = M22 * Qm[2][2];
        float nv[3][3];
#pragma unroll
        for (int r = 0; r < 3; r++)
#pragma unroll
            for (int cc = 0; cc < 3; cc++)
                nv[r][cc] = Vt[r][0] * Qm[0][cc] + Vt[r][1] * Qm[1][cc] + Vt[r][2] * Qm[2][cc];
#pragma unroll
        for (int r = 0; r < 3; r++)
#pragma unroll
            for (int cc = 0; cc < 3; cc++) Vt[r][cc] = nv[r][cc];
    }

    // pass B: z-column sum + abs-max
    float s2 = 0.f, mx01 = 0.f, mx2 = 0.f;
#pragma unroll
    for (int k = 0; k < K_; k++) {
        float4 Cv = cloud[bu[k] & 0x7FF];
        float ccx = Cv.x - px, ccy = Cv.y - py, ccz = Cv.z - pz;
        float d0 = ccx * Vt[0][0] + ccy * Vt[1][0] + ccz * Vt[2][0];
        float d1 = ccx * Vt[0][1] + ccy * Vt[1][1] + ccz * Vt[2][1];
        float d2 = ccx * Vt[0][2] + ccy * Vt[1][2] + ccz * Vt[2][2];
        s2 += d2;
        mx01 = fmaxf(mx01, fmaxf(fabsf(d0), fabsf(d1)));
        mx2  = fmaxf(mx2, fabsf(d2));
    }
    float sg = (s2 > 0.f) ? 1.f : ((s2 < 0.f) ? -1.f : 0.f);
    float mx = fmaxf(mx01, (sg == 0.f) ? 0.f : mx2);
    float hs = 0.5f / mx;

    // pass C: STATIC two-level select of this lane's 4 keys (bu stays in VGPRs)
    {
        int i = base + il;
        float4* row = (float4*)(dcn + (size_t)i * 48);
        bool od = (s & 1) != 0, hi = (s & 2) != 0;
        unsigned lo0 = od ? bu[4]  : bu[0],  hi0 = od ? bu[12] : bu[8];
        unsigned lo1 = od ? bu[5]  : bu[1],  hi1 = od ? bu[13] : bu[9];
        unsigned lo2 = od ? bu[6]  : bu[2],  hi2 = od ? bu[14] : bu[10];
        unsigned lo3 = od ? bu[7]  : bu[3],  hi3 = od ? bu[15] : bu[11];
        unsigned u0 = hi ? hi0 : lo0;
        unsigned u1 = hi ? hi1 : lo1;
        unsigned u2 = hi ? hi2 : lo2;
        unsigned u3 = hi ? hi3 : lo3;
        float v[12];
        float4 Cv;
        Cv = cloud[u0 & 0x7FF];
        {
            float ccx = Cv.x - px, ccy = Cv.y - py, ccz = Cv.z - pz;
            float d2 = (ccx * Vt[0][2] + ccy * Vt[1][2] + ccz * Vt[2][2]) * sg;
            v[0] = (ccx * Vt[0][0] + ccy * Vt[1][0] + ccz * Vt[2][0]) * hs + 0.5f;
            v[1] = (ccx * Vt[0][1] + ccy * Vt[1][1] + ccz * Vt[2][1]) * hs + 0.5f;
            v[2] = d2 * hs + 0.5f;
        }
        Cv = cloud[u1 & 0x7FF];
        {
            float ccx = Cv.x - px, ccy = Cv.y - py, ccz = Cv.z - pz;
            float d2 = (ccx * Vt[0][2] + ccy * Vt[1][2] + ccz * Vt[2][2]) * sg;
            v[3] = (ccx * Vt[0][0] + ccy * Vt[1][0] + ccz * Vt[2][0]) * hs + 0.5f;
            v[4] = (ccx * Vt[0][1] + ccy * Vt[1][1] + ccz * Vt[2][1]) * hs + 0.5f;
            v[5] = d2 * hs + 0.5f;
        }
        Cv = cloud[u2 & 0x7FF];
        {
            float ccx = Cv.x - px, ccy = Cv.y - py, ccz = Cv.z - pz;
            float d2 = (ccx * Vt[0][2] + ccy * Vt[1][2] + ccz * Vt[2][2]) * sg;
            v[6] = (ccx * Vt[0][0] + ccy * Vt[1][0] + ccz * Vt[2][0]) * hs + 0.5f;
            v[7] = (ccx * Vt[0][1] + ccy * Vt[1][1] + ccz * Vt[2][1]) * hs + 0.5f;
            v[8] = d2 * hs + 0.5f;
        }
        Cv = cloud[u3 & 0x7FF];
        {
            float ccx = Cv.x - px, ccy = Cv.y - py, ccz = Cv.z - pz;
            float d2 = (ccx * Vt[0][2] + ccy * Vt[1][2] + ccz * Vt[2][2]) * sg;
            v[9]  = (ccx * Vt[0][0] + ccy * Vt[1][0] + ccz * Vt[2][0]) * hs + 0.5f;
            v[10] = (ccx * Vt[0][1] + ccy * Vt[1][1] + ccz * Vt[2][1]) * hs + 0.5f;
            v[11] = d2 * hs + 0.5f;
        }
        row[s * 3 + 0] = make_float4(v[0], v[1], v[2], v[3]);
        row[s * 3 + 1] = make_float4(v[4], v[5], v[6], v[7]);
        row[s * 3 + 2] = make_float4(v[8], v[9], v[10], v[11]);
    }
}

// ---------- Kernel 2: trilinear spline gather (round-15 form, best tail) -----
__global__ __launch_bounds__(256) void spline_kernel(const float* __restrict__ dcn,
                                                     const float* __restrict__ w_spline,
                                                     const float* __restrict__ w_root,
                                                     const float* __restrict__ b_spline,
                                                     float* __restrict__ x,
                                                     float* __restrict__ partials) {
    __shared__ float ws_t[F_ * KS3_];   // [f][cell], 32000 B
    __shared__ float red[4][64];
    {
        int f = threadIdx.x & 63;
        for (int c = threadIdx.x >> 6; c < KS3_; c += 4)
            ws_t[f * KS3_ + c] = w_spline[c * 64 + f];
    }
    __syncthreads();
    int wave = threadIdx.x >> 6, f = threadIdx.x & 63;
    const float* wbase = &ws_t[f * KS3_];
    float wr = w_root[f] + b_spline[f];
    float s1 = 0.f, s2 = 0.f;
    for (int p = 0; p < 16; p++) {
        int i = blockIdx.x * 64 + wave * 16 + p;
        const float4* row = (const float4*)(dcn + (size_t)i * 48);
        float pr[48];
#pragma unroll
        for (int m = 0; m < 12; m++) {
            float4 v = row[m];
            pr[m * 4 + 0] = v.x; pr[m * 4 + 1] = v.y;
            pr[m * 4 + 2] = v.z; pr[m * 4 + 3] = v.w;
        }
        float acc = 0.f;
#pragma unroll
        for (int k = 0; k < K_; k++) {
            float p0 = pr[k * 3 + 0] * 4.f;
            float p1 = pr[k * 3 + 1] * 4.f;
            float p2 = pr[k * 3 + 2] * 4.f;
            float i0 = fminf(fmaxf(floorf(p0), 0.f), 3.f);
            float i1 = fminf(fmaxf(floorf(p1), 0.f), 3.f);
            float i2 = fminf(fmaxf(floorf(p2), 0.f), 3.f);
            float f0 = p0 - i0, f1 = p1 - i1, f2 = p2 - i2;
            float g0 = 1.f - f0, g1 = 1.f - f1, g2 = 1.f - f2;
            int c = (int)fmaf(i2, 25.f, fmaf(i1, 5.f, i0));
            const float* wp = wbase + c;
            float a0 = wp[0],  a1 = wp[1];
            float b0 = wp[5],  b1v = wp[6];
            float c0 = wp[25], c1 = wp[26];
            float d0 = wp[30], d1 = wp[31];
            float wA = g1 * g2, wB = f1 * g2, wC = g1 * f2, wD = f1 * f2;
            acc = fmaf(wA, fmaf(f0, a1, g0 * a0), acc);
            acc = fmaf(wB, fmaf(f0, b1v, g0 * b0), acc);
            acc = fmaf(wC, fmaf(f0, c1, g0 * c0), acc);
            acc = fmaf(wD, fmaf(f0, d1, g0 * d0), acc);
        }
        float xv = acc * (1.f / 16.f) + wr;
        x[(size_t)i * 64 + f] = xv;
        s1 += xv; s2 += xv * xv;
    }
    red[wave][f] = s1; __syncthreads();
    if (threadIdx.x < 64)
        partials[blockIdx.x * 128 + f] = red[0][f] + red[1][f] + red[2][f] + red[3][f];
    __syncthreads();
    red[wave][f] = s2; __syncthreads();
    if (threadIdx.x < 64)
        partials[blockIdx.x * 128 + 64 + f] = red[0][f] + red[1][f] + red[2][f] + red[3][f];
}

// ----------------------- Kernel 3: BN stats finalize -------------------------
__global__ __launch_bounds__(256) void stats_kernel(const float* __restrict__ partials,
                                                    const float* __restrict__ gamma,
                                                    const float* __restrict__ beta,
                                                    float* __restrict__ stats) {
    __shared__ double red1[256], red2[256];
    int t = threadIdx.x;
    int f = t & 63, g = t >> 6;
    double a0 = 0, a1 = 0, a2 = 0, a3 = 0, q0 = 0, q1 = 0, q2 = 0, q3 = 0;
    for (int b2 = g; b2 < 1024; b2 += 16) {
        a0 += (double)partials[(b2     ) * 128 + f];
        q0 += (double)partials[(b2     ) * 128 + 64 + f];
        a1 += (double)partials[(b2 +  4) * 128 + f];
        q1 += (double)partials[(b2 +  4) * 128 + 64 + f];
        a2 += (double)partials[(b2 +  8) * 128 + f];
        q2 += (double)partials[(b2 +  8) * 128 + 64 + f];
        a3 += (double)partials[(b2 + 12) * 128 + f];
        q3 += (double)partials[(b2 + 12) * 128 + 64 + f];
    }
    red1[t] = (a0 + a1) + (a2 + a3);
    red2[t] = (q0 + q1) + (q2 + q3);
    __syncthreads();
    if (t < 64) {
        double S1 = red1[t] + red1[t + 64] + red1[t + 128] + red1[t + 192];
        double S2 = red2[t] + red2[t + 64] + red2[t + 128] + red2[t + 192];
        double mu = S1 / (double)N_;
        double var = S2 / (double)N_ - mu * mu;
        double scale = (double)gamma[t] / sqrt(var + (double)EPS_);
        double shift = (double)beta[t] - mu * scale;
        stats[t] = (float)scale;
        stats[64 + t] = (float)shift;
    }
}

// -------------- Kernel 4: sigmoid + per-batch-chunk partial pool -------------
__global__ __launch_bounds__(256) void pool_partial_kernel(const float* __restrict__ x,
                                                           const float* __restrict__ stats,
                                                           float* __restrict__ pp) {
    __shared__ float red[4][64];
    int blk = blockIdx.x;            // 32 batches * 32 chunks of 64 rows
    int b = blk >> 5, ch = blk & 31;
    int f = threadIdx.x & 63, w = threadIdx.x >> 6;
    float scale = stats[f], shift = stats[64 + f];
    float acc = 0.f;
    int row0 = b * P_ + ch * 64;
    for (int r = w; r < 64; r += 4) {
        float v = x[(size_t)(row0 + r) * 64 + f];
        float t = fmaf(v, scale, shift);
        acc += __fdividef(1.f, 1.f + __expf(-t));
    }
    red[w][f] = acc; __syncthreads();
    if (threadIdx.x < 64) pp[blk * 64 + f] = red[0][f] + red[1][f] + red[2][f] + red[3][f];
}

// --------- Kernel 5: batch means + GEMM1 + ELU + GEMM2 + log_softmax --------
__global__ __launch_bounds__(256) void mlp_kernel(const float* __restrict__ pp,
                                                  const float* __restrict__ w1,
                                                  const float* __restrict__ b1,
                                                  const float* __restrict__ w2,
                                                  const float* __restrict__ b2,
                                                  float* __restrict__ out) {
    __shared__ float ssy[64];
    __shared__ float sy1[256];
    int b = blockIdx.x, t = threadIdx.x;
    if (t < 64) {
        float s = 0.f;
#pragma unroll
        for (int g = 0; g < 32; g++) s += pp[(b * 32 + g) * 64 + t];
        ssy[t] = s * (1.f / 2048.f);
    }
    __syncthreads();
    {
        float acc = b1[t];
#pragma unroll 8
        for (int c = 0; c < F_; c++) acc = fmaf(ssy[c], w1[c * 256 + t], acc);
        sy1[t] = acc > 0.f ? acc : expm1f(acc);
    }
    __syncthreads();
    if (t < 64) {
        int j = t;
        float acc = -INFINITY;
        if (j < NC_) {
            acc = b2[j];
#pragma unroll 8
            for (int c = 0; c < H_; c++) acc = fmaf(sy1[c], w2[c * 40 + j], acc);
        }
        float m = acc;
#pragma unroll
        for (int o = 32; o > 0; o >>= 1) m = fmaxf(m, __shfl_xor(m, o, 64));
        float e = (j < NC_) ? expf(acc - m) : 0.f;
        float s = e;
#pragma unroll
        for (int o = 32; o > 0; o >>= 1) s += __shfl_xor(s, o, 64);
        if (j < NC_) out[b * NC_ + j] = acc - m - logf(s);
    }
}

extern "C" void kernel_launch(void* const* d_in, const int* in_sizes, int n_in,
                              void* d_out, int out_size, void* d_ws, size_t ws_size,
                              hipStream_t stream) {
    const float* pos      = (const float*)d_in[0];
    const float* w_spline = (const float*)d_in[2];
    const float* w_root   = (const float*)d_in[3];
    const float* b_spline = (const float*)d_in[4];
    const float* bn_gamma = (const float*)d_in[5];
    const float* bn_beta  = (const float*)d_in[6];
    const float* w1       = (const float*)d_in[7];
    const float* b1       = (const float*)d_in[8];
    const float* w2       = (const float*)d_in[9];
    const float* b2       = (const float*)d_in[10];
    float* out = (float*)d_out;

    char* ws = (char*)d_ws;
    float* dcn      = (float*)(ws + 0);                    // 12 MB
    float* x        = (float*)(ws + (12u << 20));          // 16 MB
    float* partials = (float*)(ws + (28u << 20));          // 512 KB
    float* stats    = (float*)(ws + (28u << 20) + (512u << 10));               // 4 KB slot
    float* pp       = (float*)(ws + (28u << 20) + (512u << 10) + 4096);        // 256 KB

    knn_geom_kernel<<<B_ * 16, 512, 0, stream>>>(pos, dcn);
    spline_kernel<<<N_ / 64, 256, 0, stream>>>(dcn, w_spline, w_root, b_spline, x, partials);
    stats_kernel<<<1, 256, 0, stream>>>(partials, bn_gamma, bn_beta, stats);
    pool_partial_kernel<<<B_ * 32, 256, 0, stream>>>(x, stats, pp);
    mlp_kernel<<<B_, 256, 0, stream>>>(pp, w1, b1, w2, b2, out);
}